// Round 11
// baseline (1251.163 us; speedup 1.0000x reference)
//
#include <hip/hip_runtime.h>

#define DEV __device__ __forceinline__
typedef unsigned short u16;
typedef unsigned int u32;
typedef __bf16 bf16x8 __attribute__((ext_vector_type(8)));
typedef float f32x4 __attribute__((ext_vector_type(4)));

static constexpr int B = 8192, T = 90, F = 7, H = 128, NOUT = 30;
// logistic scale constants folded into weights: KS for sigmoid gates (i,f,o),
// KG for the tanh gate (g). Carry is kept in the scaled domain cs = KG * c.
#define KS (-1.44269504088896341f)
#define KG (-2.88539008177792681f)

DEV float fexp2(float x) { return __builtin_amdgcn_exp2f(x); }
DEV float frcp(float x) { return __builtin_amdgcn_rcpf(x); }
DEV float frsq(float x) { return __builtin_amdgcn_rsqf(x); }
DEV u16 f2bfbits(float f) { __bf16 b = (__bf16)f; return __builtin_bit_cast(u16, b); }
DEV float bfbits2f(u32 u) { return __builtin_bit_cast(float, u << 16); }
DEV u32 pk2(float a, float b) { return (u32)f2bfbits(a) | ((u32)f2bfbits(b) << 16); }

DEV float wave_sum(float v) {
#pragma unroll
    for (int m = 32; m; m >>= 1) v += __shfl_xor(v, m, 64);
    return v;
}

// ---------------------------------------------------------------------------
// prep_aux (R8): Uhat rows pre-scaled by the gate's logistic constant; LSTM
// bias folded into column 9 (const-1 slot of the augmented z).
// ---------------------------------------------------------------------------
__global__ __launch_bounds__(512) void prep_aux(
    const float* __restrict__ W_in, const float* __restrict__ b_in,
    const float* __restrict__ g_in, const float* __restrict__ be_in,
    const float* __restrict__ Wih0, const float* __restrict__ bih0,
    const float* __restrict__ bhh0, float* __restrict__ aux, u16* __restrict__ Uhat) {
    const int tid = threadIdx.x;
    if (tid < 7) {
        float sm = 0.f, sp = 0.f;
        for (int h = 0; h < 128; ++h) { const float w = W_in[h * 7 + tid]; sm += w; sp += w * b_in[h]; }
        aux[tid] = sm * (1.f / 128.f); aux[64 + tid] = sp * (1.f / 128.f);
    } else if (tid < 56) {
        const int cd = tid - 7, cc = cd / 7, dd = cd % 7;
        float s = 0.f;
        for (int h = 0; h < 128; ++h) s += W_in[h * 7 + cc] * W_in[h * 7 + dd];
        aux[8 + cd] = s * (1.f / 128.f);
    } else if (tid == 56) {
        float s = 0.f; for (int h = 0; h < 128; ++h) s += b_in[h];
        aux[7] = s * (1.f / 128.f);
    } else if (tid == 57) {
        float s = 0.f; for (int h = 0; h < 128; ++h) s += b_in[h] * b_in[h];
        aux[72] = s * (1.f / 128.f);
    }
    float acc[10];
#pragma unroll
    for (int i = 0; i < 10; ++i) acc[i] = 0.f;
    const float* wr = Wih0 + (long)tid * 128;
    for (int h = 0; h < 128; ++h) {
        const float wv = wr[h], wg = wv * g_in[h];
#pragma unroll
        for (int cc = 0; cc < 7; ++cc) acc[cc] += wg * W_in[h * 7 + cc];
        acc[7] += wg * b_in[h]; acc[8] += wg; acc[9] += wv * be_in[h];
    }
    acc[9] += bih0[tid] + bhh0[tid];
    const float sg = ((tid >> 7) == 2) ? KG : KS;
    u16* dst = Uhat + tid * 32;
#pragma unroll
    for (int cc = 0; cc < 10; ++cc) dst[cc] = f2bfbits(acc[cc] * sg);
#pragma unroll
    for (int cc = 10; cc < 32; ++cc) dst[cc] = 0;
}

// ---------------------------------------------------------------------------
// prep_stats (R8, unchanged)
// ---------------------------------------------------------------------------
__global__ __launch_bounds__(256) void prep_stats(
    const float* __restrict__ x, const float* __restrict__ aux,
    float2* __restrict__ stats) {
    __shared__ float sa[80];
    const int tid = threadIdx.x;
    if (tid < 80) sa[tid] = aux[tid];
    __syncthreads();
    const long idx = (long)blockIdx.x * 256 + tid;
    const float* xr = x + idx * 7;
    float xv[7];
#pragma unroll
    for (int cc = 0; cc < 7; ++cc) xv[cc] = xr[cc];
    float mu = sa[7];
#pragma unroll
    for (int cc = 0; cc < 7; ++cc) mu += sa[cc] * xv[cc];
    float q = sa[72];
#pragma unroll
    for (int cc = 0; cc < 7; ++cc) {
        float tacc = 2.f * sa[64 + cc];
#pragma unroll
        for (int dd = 0; dd < 7; ++dd) tacc += sa[8 + cc * 7 + dd] * xv[dd];
        q += xv[cc] * tacc;
    }
    const float rstd = frsq(q - mu * mu + 1e-5f);
    stats[idx] = make_float2(rstd, -rstd * mu);
}

// ---------------------------------------------------------------------------
// Gate math (R8): scaled domain, common-denominator, 5 exp2 + 2 rcp / element.
// ---------------------------------------------------------------------------
#define GATE_R(ACC, CARR, SHROW, R)                                                     \
    {                                                                                   \
        const float ei_ = fexp2(ACC[R][0]);                                             \
        const float ef_ = fexp2(ACC[R][1]);                                             \
        const float eg_ = fexp2(ACC[R][2]);                                             \
        const float eo_ = fexp2(ACC[R][3]);                                             \
        const float bf_ = 1.f + ef_;                                                    \
        const float t1_ = (1.f + ei_) * (1.f + eg_);                                    \
        const float t2_ = __builtin_fmaf(eg_, -KG, KG);                                 \
        const float num_ = __builtin_fmaf(CARR[R], t1_, t2_ * bf_);                     \
        const float cs_ = num_ * frcp(t1_ * bf_);                                       \
        CARR[R] = cs_;                                                                  \
        const float ec_ = fexp2(cs_);                                                   \
        const float hd_ = (1.f + ec_) * (1.f + eo_);                                    \
        SHROW[hwbase + (R) * 8] = f2bfbits((1.f - ec_) * frcp(hd_));                    \
    }
// NOTE: ACC[R][G] accessor below uses acc[g][r] — wrap with a helper:
#define GATE_R4(ACCG, CARR, SHROW)                                                      \
    {                                                                                   \
        _Pragma("unroll") for (int r_ = 0; r_ < 4; ++r_) {                              \
            const float ei_ = fexp2(ACCG[0][r_]);                                       \
            const float ef_ = fexp2(ACCG[1][r_]);                                       \
            const float eg_ = fexp2(ACCG[2][r_]);                                       \
            const float eo_ = fexp2(ACCG[3][r_]);                                       \
            const float bf_ = 1.f + ef_;                                                \
            const float t1_ = (1.f + ei_) * (1.f + eg_);                                \
            const float t2_ = __builtin_fmaf(eg_, -KG, KG);                             \
            const float num_ = __builtin_fmaf(CARR[r_], t1_, t2_ * bf_);                \
            const float cs_ = num_ * frcp(t1_ * bf_);                                   \
            CARR[r_] = cs_;                                                             \
            const float ec_ = fexp2(cs_);                                               \
            const float hd_ = (1.f + ec_) * (1.f + eo_);                                \
            SHROW[hwbase + r_ * 8] = f2bfbits((1.f - ec_) * frcp(hd_));                 \
        }                                                                               \
    }

// ---------------------------------------------------------------------------
// Layer-1 LSTM, R10: 16 batch rows / block, grid 512 = 2 blocks per CU.
// __launch_bounds__(512, 4): 4 waves/EU minimum -> allows 2 co-resident
// 512-thread blocks per CU (the R6 attempt used (512,2) which CAPS residency
// at 1 block/CU — the experiment never ran). Two independent barrier domains
// per SIMD hide each other's barrier/latency stalls. Gate math + prescaled
// weights from R8.
// ---------------------------------------------------------------------------
__global__ __launch_bounds__(512, 4) void lstm_rec_l1(
    const float* __restrict__ x, const float2* __restrict__ stats,
    const u16* __restrict__ Uhat, const float* __restrict__ Whh,
    u16* __restrict__ hs) {
    __shared__ __align__(16) u16 s_z[2][4][16][8];   // [par][kk8][row][8] 2 KB
    __shared__ __align__(16) u16 s_h[2][16 * 128];   // [par] 8 KB

    const int tid = threadIdx.x;
    const int wave = tid >> 6, lane = tid & 63, quad = lane >> 4, n16 = lane & 15;
    const int b0 = blockIdx.x * 16;

    for (int i = tid; i < 2 * 4 * 16 * 8; i += 512) ((u16*)s_z)[i] = 0;
    for (int i = tid; i < 16 * 128; i += 512) s_h[1][i] = 0;

    bf16x8 bU[4], bWhh[4][4];
#pragma unroll
    for (int g = 0; g < 4; ++g) {
        const float sg = (g == 2) ? KG : KS;
        const int wrow = g * 128 + 16 * wave + n16;
        bU[g] = *(const bf16x8*)&Uhat[wrow * 32 + quad * 8];
#pragma unroll
        for (int kk = 0; kk < 4; ++kk) {
            const float* ph = Whh + (long)wrow * 128 + kk * 32 + quad * 8;
            bf16x8 bh;
#pragma unroll
            for (int j = 0; j < 8; ++j) bh[j] = (__bf16)(ph[j] * sg);
            bWhh[g][kk] = bh;
        }
    }

    const f32x4 zero4 = {0.f, 0.f, 0.f, 0.f};
    float c[4];
#pragma unroll
    for (int r = 0; r < 4; ++r) c[r] = 0.f;

    // staging: 4 lanes/wave, 32 units cover 16 rows x 2 z-slices
    const bool stager = (lane < 4);
    const int tau = wave * 4 + lane;
    const int srow = tau & 15, skk8 = tau >> 4;
    const long srowg = (long)(b0 + srow) * T;

    // flush map (tid<256): 16 rows x 16 col-chunks
    const int fm = tid & 15, fkk8 = (tid >> 4) & 15;
    const int fldsoff = (fkk8 * 16 + fm) * 8;
    const size_t fgrow = (size_t)(b0 + fm) * T;
    const int fgcol = fkk8 * 8;

    const int hwbase = (2 * wave + (n16 >> 3)) * 128 + quad * 32 + (n16 & 7);

    __syncthreads();  // zero-init visible before prologue staging stores

    if (stager) {  // stage z(0) -> parity 0
        const float2 st0 = stats[srowg];
        u32 p0, p1, p2, p3;
        if (skk8 == 0) {
            const float* xp = x + srowg * 7;
            const float rs = st0.x;
            p0 = pk2(rs * xp[0], rs * xp[1]); p1 = pk2(rs * xp[2], rs * xp[3]);
            p2 = pk2(rs * xp[4], rs * xp[5]); p3 = pk2(rs * xp[6], rs);
        } else { p0 = pk2(st0.y, 1.f); p1 = 0; p2 = 0; p3 = 0; }
        *(uint4*)&s_z[0][skk8][srow][0] = (uint4){p0, p1, p2, p3};
    }
    __syncthreads();

#pragma unroll 1
    for (int t = 0; t < T; ++t) {
        const int par = t & 1;
        const bool hasPre = stager && (t + 1 < T);
        float2 nst = {};
        float nx[7];
        if (hasPre) {
            nst = stats[srowg + t + 1];
            if (skk8 == 0) {
                const float* xp = x + (srowg + t + 1) * 7;
#pragma unroll
                for (int j = 0; j < 7; ++j) nx[j] = xp[j];
            }
        }
        if (t > 0 && tid < 256) {  // flush h(t-1) from the read-side buffer
            const uint4 hv = *(const uint4*)&s_h[par ^ 1][fldsoff];
            *(uint4*)(hs + (fgrow + (t - 1)) * 128 + fgcol) = hv;
        }

        const bf16x8 az = *(const bf16x8*)&s_z[par][quad][n16][0];
        bf16x8 ah[4];
#pragma unroll
        for (int kk = 0; kk < 4; ++kk)
            ah[kk] = *(const bf16x8*)&s_h[par ^ 1][((kk * 4 + quad) * 16 + n16) * 8];
        f32x4 acc[4];
#pragma unroll
        for (int g = 0; g < 4; ++g) {
            f32x4 a = __builtin_amdgcn_mfma_f32_16x16x32_bf16(az, bU[g], zero4, 0, 0, 0);
#pragma unroll
            for (int kk = 0; kk < 4; ++kk)
                a = __builtin_amdgcn_mfma_f32_16x16x32_bf16(ah[kk], bWhh[g][kk], a, 0, 0, 0);
            acc[g] = a;
        }
        {
            u16* hp = s_h[par];
            GATE_R4(acc, c, hp)
        }

        if (hasPre) {  // commit z(t+1)
            u32 p0, p1, p2, p3;
            if (skk8 == 0) {
                const float rs = nst.x;
                p0 = pk2(rs * nx[0], rs * nx[1]); p1 = pk2(rs * nx[2], rs * nx[3]);
                p2 = pk2(rs * nx[4], rs * nx[5]); p3 = pk2(rs * nx[6], rs);
            } else { p0 = pk2(nst.y, 1.f); p1 = 0; p2 = 0; p3 = 0; }
            *(uint4*)&s_z[par ^ 1][skk8][srow][0] = (uint4){p0, p1, p2, p3};
        }
        __syncthreads();
    }
    if (tid < 256) {  // epilogue: h(T-1) at parity 1
        const uint4 hv = *(const uint4*)&s_h[1][fldsoff];
        *(uint4*)(hs + (fgrow + (T - 1)) * 128 + fgcol) = hv;
    }
}

// ---------------------------------------------------------------------------
// Layer-2 LSTM, R10: 16 rows / block, grid 512, __launch_bounds__(512,4) ->
// 2 blocks/CU. Bias in MFMA C-init (R8), prescaled weights, R8 gate math.
// ---------------------------------------------------------------------------
__global__ __launch_bounds__(512, 4) void lstm_rec_l2(
    const float* __restrict__ Wih, const float* __restrict__ Whh,
    const float* __restrict__ bih, const float* __restrict__ bhh,
    const u16* __restrict__ xin, u16* __restrict__ hlast) {
    __shared__ __align__(16) u16 s_x[2][16 * 128];   // 8 KB
    __shared__ __align__(16) u16 s_h[2][16 * 128];   // 8 KB

    const int tid = threadIdx.x;
    const int wave = tid >> 6, lane = tid & 63, quad = lane >> 4, n16 = lane & 15;
    const int b0 = blockIdx.x * 16;

    for (int i = tid; i < 16 * 128; i += 512) s_h[1][i] = 0;

    bf16x8 bWih[4][4], bWhh[4][4];
    f32x4 binit[4];
#pragma unroll
    for (int g = 0; g < 4; ++g) {
        const float sg = (g == 2) ? KG : KS;
        const int wrow = g * 128 + 16 * wave + n16;
        const float bv = (bih[wrow] + bhh[wrow]) * sg;
        binit[g] = (f32x4){bv, bv, bv, bv};
#pragma unroll
        for (int kk = 0; kk < 4; ++kk) {
            const float* pi = Wih + (long)wrow * 128 + kk * 32 + quad * 8;
            const float* ph = Whh + (long)wrow * 128 + kk * 32 + quad * 8;
            bf16x8 bi, bh;
#pragma unroll
            for (int j = 0; j < 8; ++j) { bi[j] = (__bf16)(pi[j] * sg); bh[j] = (__bf16)(ph[j] * sg); }
            bWih[g][kk] = bi; bWhh[g][kk] = bh;
        }
    }

    float c[4];
#pragma unroll
    for (int r = 0; r < 4; ++r) c[r] = 0.f;

    // staging/flush map (tid<256): 16 rows x 16 col-chunks
    const int ssm = tid & 15, sskk8 = (tid >> 4) & 15;
    const u16* gsrc = xin + (size_t)(b0 + ssm) * T * 128 + sskk8 * 8;
    const int soff = (sskk8 * 16 + ssm) * 8;

    const int hwbase = (2 * wave + (n16 >> 3)) * 128 + quad * 32 + (n16 & 7);

    if (tid < 256) {  // prologue stage x(0) -> parity 0
        const uint4 v = *(const uint4*)gsrc;
        *(uint4*)&s_x[0][soff] = v;
    }
    __syncthreads();

#pragma unroll 1
    for (int t = 0; t < T; ++t) {
        const int par = t & 1;
        uint4 pre = {};
        const bool hasPre = (t + 1 < T) && (tid < 256);
        if (hasPre) pre = *(const uint4*)(gsrc + (size_t)(t + 1) * 128);

        bf16x8 aln[4], ah[4];
#pragma unroll
        for (int kk = 0; kk < 4; ++kk) {
            const int ro = ((kk * 4 + quad) * 16 + n16) * 8;
            aln[kk] = *(const bf16x8*)&s_x[par][ro];
            ah[kk] = *(const bf16x8*)&s_h[par ^ 1][ro];
        }
        f32x4 acc[4];
#pragma unroll
        for (int g = 0; g < 4; ++g) {
            f32x4 a = __builtin_amdgcn_mfma_f32_16x16x32_bf16(aln[0], bWih[g][0], binit[g], 0, 0, 0);
            a = __builtin_amdgcn_mfma_f32_16x16x32_bf16(ah[0], bWhh[g][0], a, 0, 0, 0);
#pragma unroll
            for (int kk = 1; kk < 4; ++kk) {
                a = __builtin_amdgcn_mfma_f32_16x16x32_bf16(aln[kk], bWih[g][kk], a, 0, 0, 0);
                a = __builtin_amdgcn_mfma_f32_16x16x32_bf16(ah[kk], bWhh[g][kk], a, 0, 0, 0);
            }
            acc[g] = a;
        }
        {
            u16* hp = s_h[par];
            GATE_R4(acc, c, hp)
        }
        if (hasPre) *(uint4*)&s_x[par ^ 1][soff] = pre;
        __syncthreads();
    }
    if (tid < 256) {  // h(T-1) written at parity 1
        const uint4 hv = *(const uint4*)&s_h[1][soff];
        *(uint4*)(hlast + (size_t)(b0 + ssm) * 128 + sskk8 * 8) = hv;
    }
}

// ---------------------------------------------------------------------------
// Head: 4 rows per wave, 16 rows per block, grid 512. (unchanged)
// ---------------------------------------------------------------------------
__global__ __launch_bounds__(256) void dense_head(
    const u16* __restrict__ hlast, const float* __restrict__ g_ln,
    const float* __restrict__ be_ln, const float* __restrict__ W_d1,
    const float* __restrict__ b_d1, const float* __restrict__ W_d2,
    const float* __restrict__ b_d2, const float* __restrict__ W_d3,
    const float* __restrict__ b_d3, float* __restrict__ out) {
    __shared__ float s_ln[16][128];
    __shared__ float s_d1[16][128];
    __shared__ float s_d2[16][64];
    const int wave = threadIdx.x >> 6, lane = threadIdx.x & 63;
    const long base = (long)blockIdx.x * 16;
    const int R = wave * 4;

#pragma unroll
    for (int rr = 0; rr < 4; ++rr) {
        const long row = base + R + rr;
        const u32 packed = ((const u32*)hlast)[row * 64 + lane];
        float v0 = bfbits2f(packed & 0xffffu), v1 = bfbits2f(packed >> 16);
        const float s = wave_sum(v0 + v1);
        const float q = wave_sum(v0 * v0 + v1 * v1);
        const float mu = s * (1.f / 128.f);
        const float rstd = frsq(q * (1.f / 128.f) - mu * mu + 1e-5f);
        const int h0 = 2 * lane;
        s_ln[R + rr][h0] = (v0 - mu) * rstd * g_ln[h0] + be_ln[h0];
        s_ln[R + rr][h0 + 1] = (v1 - mu) * rstd * g_ln[h0 + 1] + be_ln[h0 + 1];
    }
    __syncthreads();

#pragma unroll
    for (int half = 0; half < 2; ++half) {
        const int o = lane + 64 * half;
        float a[4] = {b_d1[o], b_d1[o], b_d1[o], b_d1[o]};
        const float4* wr = (const float4*)(W_d1 + (long)o * 128);
#pragma unroll 8
        for (int k = 0; k < 32; ++k) {
            const float4 wv = wr[k];
#pragma unroll
            for (int rr = 0; rr < 4; ++rr) {
                const float4 xv = ((const float4*)s_ln[R + rr])[k];
                a[rr] += wv.x * xv.x + wv.y * xv.y + wv.z * xv.z + wv.w * xv.w;
            }
        }
#pragma unroll
        for (int rr = 0; rr < 4; ++rr) s_d1[R + rr][o] = fmaxf(a[rr], 0.f);
    }
    __syncthreads();

    {
        float a[4] = {b_d2[lane], b_d2[lane], b_d2[lane], b_d2[lane]};
        const float4* wr = (const float4*)(W_d2 + (long)lane * 128);
#pragma unroll 8
        for (int k = 0; k < 32; ++k) {
            const float4 wv = wr[k];
#pragma unroll
            for (int rr = 0; rr < 4; ++rr) {
                const float4 xv = ((const float4*)s_d1[R + rr])[k];
                a[rr] += wv.x * xv.x + wv.y * xv.y + wv.z * xv.z + wv.w * xv.w;
            }
        }
#pragma unroll
        for (int rr = 0; rr < 4; ++rr) s_d2[R + rr][lane] = fmaxf(a[rr], 0.f);
    }
    __syncthreads();

    if (lane < NOUT) {
        float a[4] = {b_d3[lane], b_d3[lane], b_d3[lane], b_d3[lane]};
        const float4* wr = (const float4*)(W_d3 + (long)lane * 64);
#pragma unroll
        for (int k = 0; k < 16; ++k) {
            const float4 wv = wr[k];
#pragma unroll
            for (int rr = 0; rr < 4; ++rr) {
                const float4 xv = ((const float4*)s_d2[R + rr])[k];
                a[rr] += wv.x * xv.x + wv.y * xv.y + wv.z * xv.z + wv.w * xv.w;
            }
        }
#pragma unroll
        for (int rr = 0; rr < 4; ++rr) out[(base + R + rr) * NOUT + lane] = a[rr];
    }
}

// ---------------------------------------------------------------------------
extern "C" void kernel_launch(void* const* d_in, const int* in_sizes, int n_in,
                              void* d_out, int out_size, void* d_ws, size_t ws_size,
                              hipStream_t stream) {
    const float* x = (const float*)d_in[0];
    const float* W_in = (const float*)d_in[1];
    const float* b_in = (const float*)d_in[2];
    const float* g_in = (const float*)d_in[3];
    const float* be_in = (const float*)d_in[4];
    const float* Wih0 = (const float*)d_in[5];
    const float* Whh0 = (const float*)d_in[6];
    const float* bih0 = (const float*)d_in[7];
    const float* bhh0 = (const float*)d_in[8];
    const float* Wih1 = (const float*)d_in[9];
    const float* Whh1 = (const float*)d_in[10];
    const float* bih1 = (const float*)d_in[11];
    const float* bhh1 = (const float*)d_in[12];
    const float* g_ln = (const float*)d_in[13];
    const float* be_ln = (const float*)d_in[14];
    const float* W_d1 = (const float*)d_in[15];
    const float* b_d1 = (const float*)d_in[16];
    const float* W_d2 = (const float*)d_in[17];
    const float* b_d2 = (const float*)d_in[18];
    const float* W_d3 = (const float*)d_in[19];
    const float* b_d3 = (const float*)d_in[20];
    float* out = (float*)d_out;

    // workspace layout (~197 MB): aux | Uhat | stats | hs0 | hlast
    char* w = (char*)d_ws;
    float* aux = (float*)w;               w += 512;
    u16* Uhat = (u16*)w;                  w += 512 * 32 * sizeof(u16);
    float2* stats = (float2*)w;           w += (size_t)B * T * sizeof(float2);
    u16* hs0 = (u16*)w;                   w += (size_t)B * T * H * sizeof(u16);
    u16* hlast = (u16*)w;

    prep_aux<<<1, 512, 0, stream>>>(W_in, b_in, g_in, be_in, Wih0, bih0, bhh0, aux, Uhat);
    prep_stats<<<(B * T) / 256, 256, 0, stream>>>(x, aux, stats);
    lstm_rec_l1<<<B / 16, 512, 0, stream>>>(x, stats, Uhat, Whh0, hs0);
    lstm_rec_l2<<<B / 16, 512, 0, stream>>>(Wih1, Whh1, bih1, bhh1, hs0, hlast);
    dense_head<<<B / 16, 256, 0, stream>>>(hlast, g_ln, be_ln, W_d1, b_d1, W_d2, b_d2,
                                           W_d3, b_d3, out);
}

// Round 12
// 483.743 us; speedup vs baseline: 2.5864x; 2.5864x over previous
//
#include <hip/hip_runtime.h>

#define DEV __device__ __forceinline__
typedef unsigned short u16;
typedef unsigned int u32;
typedef __bf16 bf16x8 __attribute__((ext_vector_type(8)));
typedef float f32x4 __attribute__((ext_vector_type(4)));

static constexpr int B = 8192, T = 90, F = 7, H = 128, NOUT = 30;
// logistic scale constants folded into weights: KS for sigmoid gates (i,f,o),
// KG for the tanh gate (g). Carry is kept in the scaled domain cs = KG * c.
#define KS (-1.44269504088896341f)
#define KG (-2.88539008177792681f)

DEV float fexp2(float x) { return __builtin_amdgcn_exp2f(x); }
DEV float frcp(float x) { return __builtin_amdgcn_rcpf(x); }
DEV float frsq(float x) { return __builtin_amdgcn_rsqf(x); }
DEV u16 f2bfbits(float f) { __bf16 b = (__bf16)f; return __builtin_bit_cast(u16, b); }
DEV float bfbits2f(u32 u) { return __builtin_bit_cast(float, u << 16); }
DEV u32 pk2(float a, float b) { return (u32)f2bfbits(a) | ((u32)f2bfbits(b) << 16); }

DEV float wave_sum(float v) {
#pragma unroll
    for (int m = 32; m; m >>= 1) v += __shfl_xor(v, m, 64);
    return v;
}

// ---------------------------------------------------------------------------
// prep_aux (R8): Uhat rows pre-scaled by the gate's logistic constant; LSTM
// bias folded into column 9 (const-1 slot of the augmented z).
// ---------------------------------------------------------------------------
__global__ __launch_bounds__(512) void prep_aux(
    const float* __restrict__ W_in, const float* __restrict__ b_in,
    const float* __restrict__ g_in, const float* __restrict__ be_in,
    const float* __restrict__ Wih0, const float* __restrict__ bih0,
    const float* __restrict__ bhh0, float* __restrict__ aux, u16* __restrict__ Uhat) {
    const int tid = threadIdx.x;
    if (tid < 7) {
        float sm = 0.f, sp = 0.f;
        for (int h = 0; h < 128; ++h) { const float w = W_in[h * 7 + tid]; sm += w; sp += w * b_in[h]; }
        aux[tid] = sm * (1.f / 128.f); aux[64 + tid] = sp * (1.f / 128.f);
    } else if (tid < 56) {
        const int cd = tid - 7, cc = cd / 7, dd = cd % 7;
        float s = 0.f;
        for (int h = 0; h < 128; ++h) s += W_in[h * 7 + cc] * W_in[h * 7 + dd];
        aux[8 + cd] = s * (1.f / 128.f);
    } else if (tid == 56) {
        float s = 0.f; for (int h = 0; h < 128; ++h) s += b_in[h];
        aux[7] = s * (1.f / 128.f);
    } else if (tid == 57) {
        float s = 0.f; for (int h = 0; h < 128; ++h) s += b_in[h] * b_in[h];
        aux[72] = s * (1.f / 128.f);
    }
    float acc[10];
#pragma unroll
    for (int i = 0; i < 10; ++i) acc[i] = 0.f;
    const float* wr = Wih0 + (long)tid * 128;
    for (int h = 0; h < 128; ++h) {
        const float wv = wr[h], wg = wv * g_in[h];
#pragma unroll
        for (int cc = 0; cc < 7; ++cc) acc[cc] += wg * W_in[h * 7 + cc];
        acc[7] += wg * b_in[h]; acc[8] += wg; acc[9] += wv * be_in[h];
    }
    acc[9] += bih0[tid] + bhh0[tid];
    const float sg = ((tid >> 7) == 2) ? KG : KS;
    u16* dst = Uhat + tid * 32;
#pragma unroll
    for (int cc = 0; cc < 10; ++cc) dst[cc] = f2bfbits(acc[cc] * sg);
#pragma unroll
    for (int cc = 10; cc < 32; ++cc) dst[cc] = 0;
}

// ---------------------------------------------------------------------------
// prep_stats, R11: emits the per-(b,t) MFMA A-fragments of the augmented z
// directly: zf[idx*2+0] = (rs*x0..rs*x6, rs) bf16x8; zf[idx*2+1] =
// (-rs*mu, 1, 0...). l1 lanes load their fragment straight from global.
// ---------------------------------------------------------------------------
__global__ __launch_bounds__(256) void prep_stats(
    const float* __restrict__ x, const float* __restrict__ aux,
    uint4* __restrict__ zf) {
    __shared__ float sa[80];
    const int tid = threadIdx.x;
    if (tid < 80) sa[tid] = aux[tid];
    __syncthreads();
    const long idx = (long)blockIdx.x * 256 + tid;
    const float* xr = x + idx * 7;
    float xv[7];
#pragma unroll
    for (int cc = 0; cc < 7; ++cc) xv[cc] = xr[cc];
    float mu = sa[7];
#pragma unroll
    for (int cc = 0; cc < 7; ++cc) mu += sa[cc] * xv[cc];
    float q = sa[72];
#pragma unroll
    for (int cc = 0; cc < 7; ++cc) {
        float tacc = 2.f * sa[64 + cc];
#pragma unroll
        for (int dd = 0; dd < 7; ++dd) tacc += sa[8 + cc * 7 + dd] * xv[dd];
        q += xv[cc] * tacc;
    }
    const float rstd = frsq(q - mu * mu + 1e-5f);
    zf[idx * 2 + 0] = (uint4){pk2(rstd * xv[0], rstd * xv[1]), pk2(rstd * xv[2], rstd * xv[3]),
                              pk2(rstd * xv[4], rstd * xv[5]), pk2(rstd * xv[6], rstd)};
    zf[idx * 2 + 1] = (uint4){pk2(-rstd * mu, 1.f), 0u, 0u, 0u};
}

// ---------------------------------------------------------------------------
// Gate math (R8): scaled domain, common-denominator, 5 exp2 + 2 rcp / element.
// ACC[g][r] = scaled pre-activation INCLUDING bias. CARR holds cs.
// ---------------------------------------------------------------------------
#define GATE_R(ACC, CARR, SHROW, R)                                                     \
    {                                                                                   \
        const float ei_ = fexp2(ACC[0][R]);                                             \
        const float ef_ = fexp2(ACC[1][R]);                                             \
        const float eg_ = fexp2(ACC[2][R]);                                             \
        const float eo_ = fexp2(ACC[3][R]);                                             \
        const float bf_ = 1.f + ef_;                                                    \
        const float t1_ = (1.f + ei_) * (1.f + eg_);                                    \
        const float t2_ = __builtin_fmaf(eg_, -KG, KG);                                 \
        const float num_ = __builtin_fmaf(CARR[R], t1_, t2_ * bf_);                     \
        const float cs_ = num_ * frcp(t1_ * bf_);                                       \
        CARR[R] = cs_;                                                                  \
        const float ec_ = fexp2(cs_);                                                   \
        const float hd_ = (1.f + ec_) * (1.f + eo_);                                    \
        SHROW[hwbase + (R) * 8] = f2bfbits((1.f - ec_) * frcp(hd_));                    \
    }

// ---------------------------------------------------------------------------
// Layer-1 LSTM, R11: z A-fragments loaded per-lane from global zf (register
// prefetch one step ahead; quad>=2 lanes hold constant zero) — the entire
// z staging path (s_z LDS, stats/x loads, packs, commits, z ds_reads) is
// deleted. Barrier now only guards s_h. R1 two-tile structure, R8 gate math.
// ---------------------------------------------------------------------------
__global__ __launch_bounds__(512, 2) void lstm_rec_l1(
    const uint4* __restrict__ zf, const u16* __restrict__ Uhat,
    const float* __restrict__ Whh, u16* __restrict__ hs) {
    __shared__ __align__(16) u16 s_hA[2][16 * 128];   // h parity A (t even)
    __shared__ __align__(16) u16 s_hB[2][16 * 128];   // h parity B (t odd)

    const int tid = threadIdx.x;
    const int wave = tid >> 6, lane = tid & 63, quad = lane >> 4, n16 = lane & 15;
    const int b0 = blockIdx.x * 32;

    for (int i = tid; i < 2 * 16 * 128; i += 512) ((u16*)s_hB)[i] = 0;

    bf16x8 bU[4], bWhh[4][4];
#pragma unroll
    for (int g = 0; g < 4; ++g) {
        const float sg = (g == 2) ? KG : KS;
        const int wrow = g * 128 + 16 * wave + n16;
        bU[g] = *(const bf16x8*)&Uhat[wrow * 32 + quad * 8];
#pragma unroll
        for (int kk = 0; kk < 4; ++kk) {
            const float* ph = Whh + (long)wrow * 128 + kk * 32 + quad * 8;
            bf16x8 bh;
#pragma unroll
            for (int j = 0; j < 8; ++j) bh[j] = (__bf16)(ph[j] * sg);
            bWhh[g][kk] = bh;
        }
    }

    const f32x4 zero4 = {0.f, 0.f, 0.f, 0.f};
    float c[2][4];
#pragma unroll
    for (int mt = 0; mt < 2; ++mt)
#pragma unroll
        for (int r = 0; r < 4; ++r) c[mt][r] = 0.f;

    // per-lane z fragment pointers: lane (quad,n16) reads fragment quad of its
    // tile row; only quad<2 carries nonzero data.
    const bool zl = (quad < 2);
    const int zq = quad & 1;  // safe index for inactive lanes
    const uint4* zr0 = zf + ((size_t)(b0 + n16) * T) * 2 + zq;
    const uint4* zr1 = zf + ((size_t)(b0 + 16 + n16) * T) * 2 + zq;
    uint4 cz0 = {}, cz1 = {};
    if (zl) { cz0 = zr0[0]; cz1 = zr1[0]; }

    // per-tile flush map (tid<256 tile0, else tile1): 16 rows x 16 col-chunks
    const int fm = tid & 15, fkk8 = (tid >> 4) & 15;
    const int fldsoff = (fkk8 * 16 + fm) * 8;
    const int fgcol = fkk8 * 8;

    const int hwbase = (2 * wave + (n16 >> 3)) * 128 + quad * 32 + (n16 & 7);

    __syncthreads();  // zero-init of s_hB visible

#define L1_CH(AZ, AH, G, OUT)                                                           \
    {                                                                                   \
        f32x4 a_ = __builtin_amdgcn_mfma_f32_16x16x32_bf16(AZ, bU[G], zero4, 0, 0, 0);  \
        a_ = __builtin_amdgcn_mfma_f32_16x16x32_bf16(AH[0], bWhh[G][0], a_, 0, 0, 0);   \
        a_ = __builtin_amdgcn_mfma_f32_16x16x32_bf16(AH[1], bWhh[G][1], a_, 0, 0, 0);   \
        a_ = __builtin_amdgcn_mfma_f32_16x16x32_bf16(AH[2], bWhh[G][2], a_, 0, 0, 0);   \
        a_ = __builtin_amdgcn_mfma_f32_16x16x32_bf16(AH[3], bWhh[G][3], a_, 0, 0, 0);   \
        OUT = a_;                                                                       \
    }

#define L1_STEP(TT, SHR, SHW)                                                           \
    {                                                                                   \
        const int t_ = (TT);                                                            \
        const bool hasPre = (t_ + 1 < T);                                               \
        uint4 nz0 = {}, nz1 = {};                                                       \
        if (hasPre && zl) { nz0 = zr0[(t_ + 1) * 2]; nz1 = zr1[(t_ + 1) * 2]; }         \
        if (t_ > 0) {  /* flush h(t-1) from the read-side buffer */                     \
            if (tid < 256) {                                                            \
                const uint4 hv0 = *(const uint4*)&SHR[0][fldsoff];                      \
                *(uint4*)(hs + (((size_t)(b0 + fm) * T) + (t_ - 1)) * 128 + fgcol) = hv0; \
            } else {                                                                    \
                const uint4 hv1 = *(const uint4*)&SHR[1][fldsoff];                      \
                *(uint4*)(hs + (((size_t)(b0 + 16 + fm) * T) + (t_ - 1)) * 128 + fgcol) = hv1; \
            }                                                                           \
        }                                                                               \
        const bf16x8 az0 = __builtin_bit_cast(bf16x8, cz0);                             \
        bf16x8 ah0[4];                                                                  \
        _Pragma("unroll") for (int kk = 0; kk < 4; ++kk)                                \
            ah0[kk] = *(const bf16x8*)&SHR[0][((kk * 4 + quad) * 16 + n16) * 8];        \
        f32x4 acc0[4], acc1[4];                                                         \
        L1_CH(az0, ah0, 0, acc0[0])                                                     \
        L1_CH(az0, ah0, 1, acc0[1])                                                     \
        L1_CH(az0, ah0, 2, acc0[2])                                                     \
        L1_CH(az0, ah0, 3, acc0[3])                                                     \
        const bf16x8 az1 = __builtin_bit_cast(bf16x8, cz1);                             \
        bf16x8 ah1[4];                                                                  \
        _Pragma("unroll") for (int kk = 0; kk < 4; ++kk)                                \
            ah1[kk] = *(const bf16x8*)&SHR[1][((kk * 4 + quad) * 16 + n16) * 8];        \
        L1_CH(az1, ah1, 0, acc1[0])                                                     \
        GATE_R(acc0, c[0], SHW[0], 0)                                                   \
        L1_CH(az1, ah1, 1, acc1[1])                                                     \
        GATE_R(acc0, c[0], SHW[0], 1)                                                   \
        L1_CH(az1, ah1, 2, acc1[2])                                                     \
        GATE_R(acc0, c[0], SHW[0], 2)                                                   \
        L1_CH(az1, ah1, 3, acc1[3])                                                     \
        GATE_R(acc0, c[0], SHW[0], 3)                                                   \
        GATE_R(acc1, c[1], SHW[1], 0)                                                   \
        GATE_R(acc1, c[1], SHW[1], 1)                                                   \
        GATE_R(acc1, c[1], SHW[1], 2)                                                   \
        GATE_R(acc1, c[1], SHW[1], 3)                                                   \
        cz0 = nz0; cz1 = nz1;                                                           \
        __syncthreads();                                                                \
    }

#pragma unroll 1
    for (int t = 0; t < T; t += 2) {
        L1_STEP(t, s_hB, s_hA)        // even t: read h B, write h A
        L1_STEP(t + 1, s_hA, s_hB)    // odd t: roles swapped
    }
#undef L1_STEP
#undef L1_CH
    {  // epilogue: h(T-1) was written at odd parity -> s_hB
        const int ftile = tid >> 8, finner = tid & 255;
        const int efm = finner & 15, efkk8 = finner >> 4;
        const uint4 hv = *(const uint4*)&s_hB[ftile][(efkk8 * 16 + efm) * 8];
        *(uint4*)(hs + ((size_t)(b0 + ftile * 16 + efm) * T + (T - 1)) * 128 + efkk8 * 8) = hv;
    }
}

// ---------------------------------------------------------------------------
// Layer-2 LSTM (R8 form, unchanged): bias in MFMA C-init, (512,1).
// ---------------------------------------------------------------------------
__global__ __launch_bounds__(512, 1) void lstm_rec_l2(
    const float* __restrict__ Wih, const float* __restrict__ Whh,
    const float* __restrict__ bih, const float* __restrict__ bhh,
    const u16* __restrict__ xin, u16* __restrict__ hlast) {
    __shared__ __align__(16) u16 s_xA[2][16 * 128];
    __shared__ __align__(16) u16 s_xB[2][16 * 128];
    __shared__ __align__(16) u16 s_hA[2][16 * 128];
    __shared__ __align__(16) u16 s_hB[2][16 * 128];

    const int tid = threadIdx.x;
    const int wave = tid >> 6, lane = tid & 63, quad = lane >> 4, n16 = lane & 15;
    const int b0 = blockIdx.x * 32;

    for (int i = tid; i < 2 * 16 * 128; i += 512) ((u16*)s_hB)[i] = 0;

    bf16x8 bWih[4][4], bWhh[4][4];
    f32x4 binit[4];
#pragma unroll
    for (int g = 0; g < 4; ++g) {
        const float sg = (g == 2) ? KG : KS;
        const int wrow = g * 128 + 16 * wave + n16;
        const float bv = (bih[wrow] + bhh[wrow]) * sg;
        binit[g] = (f32x4){bv, bv, bv, bv};
#pragma unroll
        for (int kk = 0; kk < 4; ++kk) {
            const float* pi = Wih + (long)wrow * 128 + kk * 32 + quad * 8;
            const float* ph = Whh + (long)wrow * 128 + kk * 32 + quad * 8;
            bf16x8 bi, bh;
#pragma unroll
            for (int j = 0; j < 8; ++j) { bi[j] = (__bf16)(pi[j] * sg); bh[j] = (__bf16)(ph[j] * sg); }
            bWih[g][kk] = bi; bWhh[g][kk] = bh;
        }
    }

    float c[2][4];
#pragma unroll
    for (int mt = 0; mt < 2; ++mt)
#pragma unroll
        for (int r = 0; r < 4; ++r) c[mt][r] = 0.f;

    const int stile = tid >> 8, sinner = tid & 255;
    const int ssm = sinner & 15, sskk8 = sinner >> 4;
    const u16* gsrc = xin + (size_t)(b0 + stile * 16 + ssm) * T * 128 + sskk8 * 8;
    const int soff = sinner * 8;

    const int hwbase = (2 * wave + (n16 >> 3)) * 128 + quad * 32 + (n16 & 7);

    {  // prologue stage x(0) -> xA
        const uint4 v = *(const uint4*)gsrc;
        *(uint4*)&s_xA[stile][soff] = v;
    }
    __syncthreads();

#define L2_CH(AX, AH, G, OUT)                                                           \
    {                                                                                   \
        f32x4 a_ = __builtin_amdgcn_mfma_f32_16x16x32_bf16(AX[0], bWih[G][0], binit[G], 0, 0, 0); \
        a_ = __builtin_amdgcn_mfma_f32_16x16x32_bf16(AH[0], bWhh[G][0], a_, 0, 0, 0);   \
        a_ = __builtin_amdgcn_mfma_f32_16x16x32_bf16(AX[1], bWih[G][1], a_, 0, 0, 0);   \
        a_ = __builtin_amdgcn_mfma_f32_16x16x32_bf16(AH[1], bWhh[G][1], a_, 0, 0, 0);   \
        a_ = __builtin_amdgcn_mfma_f32_16x16x32_bf16(AX[2], bWih[G][2], a_, 0, 0, 0);   \
        a_ = __builtin_amdgcn_mfma_f32_16x16x32_bf16(AH[2], bWhh[G][2], a_, 0, 0, 0);   \
        a_ = __builtin_amdgcn_mfma_f32_16x16x32_bf16(AX[3], bWih[G][3], a_, 0, 0, 0);   \
        a_ = __builtin_amdgcn_mfma_f32_16x16x32_bf16(AH[3], bWhh[G][3], a_, 0, 0, 0);   \
        OUT = a_;                                                                       \
    }

#define L2_STEP(TT, SXR, SXW, SHR, SHW)                                                 \
    {                                                                                   \
        const int t_ = (TT);                                                            \
        const bool hasPre = (t_ + 1 < T);                                               \
        uint4 pre = {};                                                                 \
        if (hasPre) pre = *(const uint4*)(gsrc + (size_t)(t_ + 1) * 128);               \
        bf16x8 aln0[4], ah0[4];                                                         \
        _Pragma("unroll") for (int kk = 0; kk < 4; ++kk) {                              \
            const int ro = (kk * 4 + quad) * 128 + n16 * 8;                             \
            aln0[kk] = *(const bf16x8*)&SXR[0][ro];                                     \
            ah0[kk] = *(const bf16x8*)&SHR[0][ro];                                      \
        }                                                                               \
        f32x4 acc0[4], acc1[4];                                                         \
        L2_CH(aln0, ah0, 0, acc0[0])                                                    \
        L2_CH(aln0, ah0, 1, acc0[1])                                                    \
        L2_CH(aln0, ah0, 2, acc0[2])                                                    \
        L2_CH(aln0, ah0, 3, acc0[3])                                                    \
        bf16x8 aln1[4], ah1[4];                                                         \
        _Pragma("unroll") for (int kk = 0; kk < 4; ++kk) {                              \
            const int ro = (kk * 4 + quad) * 128 + n16 * 8;                             \
            aln1[kk] = *(const bf16x8*)&SXR[1][ro];                                     \
            ah1[kk] = *(const bf16x8*)&SHR[1][ro];                                      \
        }                                                                               \
        L2_CH(aln1, ah1, 0, acc1[0])                                                    \
        GATE_R(acc0, c[0], SHW[0], 0)                                                   \
        L2_CH(aln1, ah1, 1, acc1[1])                                                    \
        GATE_R(acc0, c[0], SHW[0], 1)                                                   \
        L2_CH(aln1, ah1, 2, acc1[2])                                                    \
        GATE_R(acc0, c[0], SHW[0], 2)                                                   \
        L2_CH(aln1, ah1, 3, acc1[3])                                                    \
        GATE_R(acc0, c[0], SHW[0], 3)                                                   \
        GATE_R(acc1, c[1], SHW[1], 0)                                                   \
        GATE_R(acc1, c[1], SHW[1], 1)                                                   \
        GATE_R(acc1, c[1], SHW[1], 2)                                                   \
        GATE_R(acc1, c[1], SHW[1], 3)                                                   \
        if (hasPre) *(uint4*)&SXW[stile][soff] = pre;                                   \
        __syncthreads();                                                                \
    }

#pragma unroll 1
    for (int t = 0; t < T; t += 2) {
        L2_STEP(t, s_xA, s_xB, s_hB, s_hA)        // even t
        L2_STEP(t + 1, s_xB, s_xA, s_hA, s_hB)    // odd t
    }
#undef L2_STEP
#undef L2_CH
    {  // h(T-1) written at odd parity -> s_hB
        const uint4 hv = *(const uint4*)&s_hB[stile][(sskk8 * 16 + ssm) * 8];
        *(uint4*)(hlast + (size_t)(b0 + stile * 16 + ssm) * 128 + sskk8 * 8) = hv;
    }
}

// ---------------------------------------------------------------------------
// Head: 4 rows per wave, 16 rows per block, grid 512. (unchanged)
// ---------------------------------------------------------------------------
__global__ __launch_bounds__(256) void dense_head(
    const u16* __restrict__ hlast, const float* __restrict__ g_ln,
    const float* __restrict__ be_ln, const float* __restrict__ W_d1,
    const float* __restrict__ b_d1, const float* __restrict__ W_d2,
    const float* __restrict__ b_d2, const float* __restrict__ W_d3,
    const float* __restrict__ b_d3, float* __restrict__ out) {
    __shared__ float s_ln[16][128];
    __shared__ float s_d1[16][128];
    __shared__ float s_d2[16][64];
    const int wave = threadIdx.x >> 6, lane = threadIdx.x & 63;
    const long base = (long)blockIdx.x * 16;
    const int R = wave * 4;

#pragma unroll
    for (int rr = 0; rr < 4; ++rr) {
        const long row = base + R + rr;
        const u32 packed = ((const u32*)hlast)[row * 64 + lane];
        float v0 = bfbits2f(packed & 0xffffu), v1 = bfbits2f(packed >> 16);
        const float s = wave_sum(v0 + v1);
        const float q = wave_sum(v0 * v0 + v1 * v1);
        const float mu = s * (1.f / 128.f);
        const float rstd = frsq(q * (1.f / 128.f) - mu * mu + 1e-5f);
        const int h0 = 2 * lane;
        s_ln[R + rr][h0] = (v0 - mu) * rstd * g_ln[h0] + be_ln[h0];
        s_ln[R + rr][h0 + 1] = (v1 - mu) * rstd * g_ln[h0 + 1] + be_ln[h0 + 1];
    }
    __syncthreads();

#pragma unroll
    for (int half = 0; half < 2; ++half) {
        const int o = lane + 64 * half;
        float a[4] = {b_d1[o], b_d1[o], b_d1[o], b_d1[o]};
        const float4* wr = (const float4*)(W_d1 + (long)o * 128);
#pragma unroll 8
        for (int k = 0; k < 32; ++k) {
            const float4 wv = wr[k];
#pragma unroll
            for (int rr = 0; rr < 4; ++rr) {
                const float4 xv = ((const float4*)s_ln[R + rr])[k];
                a[rr] += wv.x * xv.x + wv.y * xv.y + wv.z * xv.z + wv.w * xv.w;
            }
        }
#pragma unroll
        for (int rr = 0; rr < 4; ++rr) s_d1[R + rr][o] = fmaxf(a[rr], 0.f);
    }
    __syncthreads();

    {
        float a[4] = {b_d2[lane], b_d2[lane], b_d2[lane], b_d2[lane]};
        const float4* wr = (const float4*)(W_d2 + (long)lane * 128);
#pragma unroll 8
        for (int k = 0; k < 32; ++k) {
            const float4 wv = wr[k];
#pragma unroll
            for (int rr = 0; rr < 4; ++rr) {
                const float4 xv = ((const float4*)s_d1[R + rr])[k];
                a[rr] += wv.x * xv.x + wv.y * xv.y + wv.z * xv.z + wv.w * xv.w;
            }
        }
#pragma unroll
        for (int rr = 0; rr < 4; ++rr) s_d2[R + rr][lane] = fmaxf(a[rr], 0.f);
    }
    __syncthreads();

    if (lane < NOUT) {
        float a[4] = {b_d3[lane], b_d3[lane], b_d3[lane], b_d3[lane]};
        const float4* wr = (const float4*)(W_d3 + (long)lane * 64);
#pragma unroll
        for (int k = 0; k < 16; ++k) {
            const float4 wv = wr[k];
#pragma unroll
            for (int rr = 0; rr < 4; ++rr) {
                const float4 xv = ((const float4*)s_d2[R + rr])[k];
                a[rr] += wv.x * xv.x + wv.y * xv.y + wv.z * xv.z + wv.w * xv.w;
            }
        }
#pragma unroll
        for (int rr = 0; rr < 4; ++rr) out[(base + R + rr) * NOUT + lane] = a[rr];
    }
}

// ---------------------------------------------------------------------------
extern "C" void kernel_launch(void* const* d_in, const int* in_sizes, int n_in,
                              void* d_out, int out_size, void* d_ws, size_t ws_size,
                              hipStream_t stream) {
    const float* x = (const float*)d_in[0];
    const float* W_in = (const float*)d_in[1];
    const float* b_in = (const float*)d_in[2];
    const float* g_in = (const float*)d_in[3];
    const float* be_in = (const float*)d_in[4];
    const float* Wih0 = (const float*)d_in[5];
    const float* Whh0 = (const float*)d_in[6];
    const float* bih0 = (const float*)d_in[7];
    const float* bhh0 = (const float*)d_in[8];
    const float* Wih1 = (const float*)d_in[9];
    const float* Whh1 = (const float*)d_in[10];
    const float* bih1 = (const float*)d_in[11];
    const float* bhh1 = (const float*)d_in[12];
    const float* g_ln = (const float*)d_in[13];
    const float* be_ln = (const float*)d_in[14];
    const float* W_d1 = (const float*)d_in[15];
    const float* b_d1 = (const float*)d_in[16];
    const float* W_d2 = (const float*)d_in[17];
    const float* b_d2 = (const float*)d_in[18];
    const float* W_d3 = (const float*)d_in[19];
    const float* b_d3 = (const float*)d_in[20];
    float* out = (float*)d_out;

    // workspace layout (~221 MB): aux | Uhat | zf | hs0 | hlast
    char* w = (char*)d_ws;
    float* aux = (float*)w;               w += 512;
    u16* Uhat = (u16*)w;                  w += 512 * 32 * sizeof(u16);
    uint4* zf = (uint4*)w;                w += (size_t)B * T * 2 * sizeof(uint4);
    u16* hs0 = (u16*)w;                   w += (size_t)B * T * H * sizeof(u16);
    u16* hlast = (u16*)w;

    prep_aux<<<1, 512, 0, stream>>>(W_in, b_in, g_in, be_in, Wih0, bih0, bhh0, aux, Uhat);
    prep_stats<<<(B * T) / 256, 256, 0, stream>>>(x, aux, zf);
    lstm_rec_l1<<<B / 32, 512, 0, stream>>>(zf, Uhat, Whh0, hs0);
    lstm_rec_l2<<<B / 32, 512, 0, stream>>>(Wih1, Whh1, bih1, bhh1, hs0, hlast);
    dense_head<<<B / 16, 256, 0, stream>>>(hlast, g_ln, be_ln, W_d1, b_d1, W_d2, b_d2,
                                           W_d3, b_d3, out);
}